// Round 1
// baseline (311.831 us; speedup 1.0000x reference)
//
#include <hip/hip_runtime.h>
#include <cmath>

#define NTOK 4096
#define CQd  8
#define CHd  64
#define QT   64
#define JT   64

// ---------------------------------------------------------------------------
// Kernel 1: QKV projection (1x1x1 conv == per-voxel matvec).
// One thread per voxel. Weights staged in LDS (broadcast reads).
// Outputs written TRANSPOSED: qt[b][i][cq], kt[b][i][cq], vt[b][i][c]
// so the attention kernel can stage tiles with straight float4 copies.
// ---------------------------------------------------------------------------
__global__ __launch_bounds__(64)
void qkv_kernel(const float* __restrict__ x,
                const float* __restrict__ Wq, const float* __restrict__ bq,
                const float* __restrict__ Wk, const float* __restrict__ bk,
                const float* __restrict__ Wv, const float* __restrict__ bv,
                float* __restrict__ qt, float* __restrict__ kt, float* __restrict__ vt)
{
    __shared__ float wlds[80 * 64];   // rows 0-7: Wq, 8-15: Wk, 16-79: Wv
    __shared__ float blds[80];
    const int t = threadIdx.x;

    float4* w4 = (float4*)wlds;
    const float4* wq4 = (const float4*)Wq;
    const float4* wk4 = (const float4*)Wk;
    const float4* wv4 = (const float4*)Wv;
    #pragma unroll
    for (int r = 0; r < 2; r++)  w4[t + 64*r]        = wq4[t + 64*r];
    #pragma unroll
    for (int r = 0; r < 2; r++)  w4[128 + t + 64*r]  = wk4[t + 64*r];
    #pragma unroll
    for (int r = 0; r < 16; r++) w4[256 + t + 64*r]  = wv4[t + 64*r];
    if (t < 8)        blds[t]      = bq[t];
    else if (t < 16)  blds[t]      = bk[t - 8];
    blds[16 + t] = bv[t];
    __syncthreads();

    const int gid = blockIdx.x * 64 + t;
    const int b = gid >> 12;
    const int i = gid & (NTOK - 1);
    const float* xb = x + ((size_t)b * CHd) * NTOK + i;
    float xv[64];
    #pragma unroll
    for (int c = 0; c < 64; c++) xv[c] = xb[(size_t)c * NTOK];

    const size_t row = (size_t)b * NTOK + i;
    for (int chunk = 0; chunk < 10; chunk++) {
        float a[8];
        #pragma unroll
        for (int o = 0; o < 8; o++) a[o] = blds[chunk*8 + o];
        #pragma unroll
        for (int c4 = 0; c4 < 16; c4++) {
            #pragma unroll
            for (int o = 0; o < 8; o++) {
                float4 w = ((const float4*)wlds)[(chunk*8 + o)*16 + c4];
                a[o] += w.x * xv[c4*4+0] + w.y * xv[c4*4+1]
                      + w.z * xv[c4*4+2] + w.w * xv[c4*4+3];
            }
        }
        float* dst;
        if (chunk == 0)      dst = qt + row * CQd;
        else if (chunk == 1) dst = kt + row * CQd;
        else                 dst = vt + row * CHd + (chunk-2)*8;
        ((float4*)dst)[0] = make_float4(a[0], a[1], a[2], a[3]);
        ((float4*)dst)[1] = make_float4(a[4], a[5], a[6], a[7]);
    }
}

// ---------------------------------------------------------------------------
// Kernel 2: flash-style attention + residual epilogue.
// Grid (NTOK/QT, B), 512 threads. 8 threads per query ("group"): sub = t&7
// owns channels sub*8..sub*8+7. Online softmax with group shfl reductions.
// p shared within group through a padded LDS tile (stride 68 floats:
// 16B-aligned, <=2-way bank aliasing which is free on CDNA4).
// ---------------------------------------------------------------------------
__global__ __launch_bounds__(512)
void attn_kernel(const float* __restrict__ qt, const float* __restrict__ kt,
                 const float* __restrict__ vt, const float* __restrict__ x,
                 const float* __restrict__ gamma, float* __restrict__ out)
{
    __shared__ float klds[JT * CQd];   // [j][8]    2 KB
    __shared__ float vlds[JT * CHd];   // [j][64]  16 KB
    __shared__ float plds[QT * 68];    // [qi][68] 17 KB (padded)

    const int t   = threadIdx.x;
    const int qi  = t >> 3;
    const int sub = t & 7;
    const int b     = blockIdx.y;
    const int qbase = blockIdx.x * QT;

    const float* qrow = qt + ((size_t)b*NTOK + qbase + qi) * CQd;
    const float4 q0 = ((const float4*)qrow)[0];
    const float4 q1 = ((const float4*)qrow)[1];

    float acc[8];
    #pragma unroll
    for (int cc = 0; cc < 8; cc++) acc[cc] = 0.f;
    float m = -INFINITY, l = 0.f;

    const float* kbase = kt + (size_t)b * NTOK * CQd;
    const float* vbase = vt + (size_t)b * NTOK * CHd;

    for (int jt = 0; jt < NTOK; jt += JT) {
        __syncthreads();   // previous tile's LDS reads done
        if (t < 128)
            ((float4*)klds)[t] = ((const float4*)(kbase + (size_t)jt*CQd))[t];
        {
            const float4* vsrc = (const float4*)(vbase + (size_t)jt*CHd);
            float4* vdst = (float4*)vlds;
            #pragma unroll
            for (int r = 0; r < 2; r++) vdst[t + 512*r] = vsrc[t + 512*r];
        }
        __syncthreads();   // tile staged

        // ---- scores: 8 j's per thread (j = sub + 8*i2) ----
        float s[8];
        float lmax = -INFINITY;
        #pragma unroll
        for (int i2 = 0; i2 < 8; i2++) {
            const int j = sub + (i2 << 3);
            const float4 k0 = ((const float4*)(klds + j*CQd))[0];
            const float4 k1 = ((const float4*)(klds + j*CQd))[1];
            float d = q0.x*k0.x + q0.y*k0.y + q0.z*k0.z + q0.w*k0.w
                    + q1.x*k1.x + q1.y*k1.y + q1.z*k1.z + q1.w*k1.w;
            s[i2] = d;
            lmax = fmaxf(lmax, d);
        }
        #pragma unroll
        for (int msk = 1; msk < 8; msk <<= 1)
            lmax = fmaxf(lmax, __shfl_xor(lmax, msk, 8));

        const float mnew  = fmaxf(m, lmax);
        const float scale = __expf(m - mnew);   // exp(-inf)=0 on first tile
        float psum = 0.f;
        #pragma unroll
        for (int i2 = 0; i2 < 8; i2++) {
            const float p = __expf(s[i2] - mnew);
            plds[qi*68 + sub + (i2 << 3)] = p;
            psum += p;
        }
        #pragma unroll
        for (int msk = 1; msk < 8; msk <<= 1)
            psum += __shfl_xor(psum, msk, 8);
        l = l * scale + psum;
        m = mnew;
        #pragma unroll
        for (int cc = 0; cc < 8; cc++) acc[cc] *= scale;
        __syncthreads();   // p visible

        // ---- PV: acc[cc] += p[j] * v[j][sub*8+cc] ----
        #pragma unroll 4
        for (int j4 = 0; j4 < JT; j4 += 4) {
            const float4 p4 = *((const float4*)(plds + qi*68 + j4));
            #pragma unroll
            for (int jj = 0; jj < 4; jj++) {
                const float4* vrow = (const float4*)(vlds + (j4+jj)*CHd + sub*8);
                const float4 v0 = vrow[0];
                const float4 v1 = vrow[1];
                const float p = (jj==0) ? p4.x : (jj==1) ? p4.y : (jj==2) ? p4.z : p4.w;
                acc[0] += p*v0.x; acc[1] += p*v0.y; acc[2] += p*v0.z; acc[3] += p*v0.w;
                acc[4] += p*v1.x; acc[5] += p*v1.y; acc[6] += p*v1.z; acc[7] += p*v1.w;
            }
        }
    }

    // ---- epilogue: transpose through LDS, add residual, coalesced store ----
    __syncthreads();
    const float ginv = gamma[0] / l;
    #pragma unroll
    for (int cc = 0; cc < 8; cc++)
        plds[(sub*8 + cc)*68 + qi] = acc[cc] * ginv;
    __syncthreads();

    const int c  = t >> 3;
    const int qq = (t & 7) << 3;
    const size_t off = (((size_t)b*CHd + c) << 12) + qbase + qq;
    const float4 x0 = ((const float4*)(x + off))[0];
    const float4 x1 = ((const float4*)(x + off))[1];
    float4 r0, r1;
    r0.x = plds[c*68 + qq+0] + x0.x;
    r0.y = plds[c*68 + qq+1] + x0.y;
    r0.z = plds[c*68 + qq+2] + x0.z;
    r0.w = plds[c*68 + qq+3] + x0.w;
    r1.x = plds[c*68 + qq+4] + x1.x;
    r1.y = plds[c*68 + qq+5] + x1.y;
    r1.z = plds[c*68 + qq+6] + x1.z;
    r1.w = plds[c*68 + qq+7] + x1.w;
    ((float4*)(out + off))[0] = r0;
    ((float4*)(out + off))[1] = r1;
}

// ---------------------------------------------------------------------------
extern "C" void kernel_launch(void* const* d_in, const int* in_sizes, int n_in,
                              void* d_out, int out_size, void* d_ws, size_t ws_size,
                              hipStream_t stream) {
    const float* x     = (const float*)d_in[0];
    const float* Wq    = (const float*)d_in[1];
    const float* bq    = (const float*)d_in[2];
    const float* Wk    = (const float*)d_in[3];
    const float* bk    = (const float*)d_in[4];
    const float* Wv    = (const float*)d_in[5];
    const float* bv    = (const float*)d_in[6];
    const float* gamma = (const float*)d_in[7];
    float* out = (float*)d_out;

    float* qt = (float*)d_ws;                       // 4*4096*8  floats
    float* kt = qt + (size_t)4 * NTOK * CQd;        // 4*4096*8  floats
    float* vt = kt + (size_t)4 * NTOK * CQd;        // 4*4096*64 floats

    qkv_kernel<<<256, 64, 0, stream>>>(x, Wq, bq, Wk, bk, Wv, bv, qt, kt, vt);
    attn_kernel<<<dim3(NTOK / QT, 4), 512, 0, stream>>>(qt, kt, vt, x, gamma, out);
}

// Round 2
// 91.509 us; speedup vs baseline: 3.4077x; 3.4077x over previous
//
#include <hip/hip_runtime.h>
#include <hip/hip_bf16.h>
#include <cmath>

#define NTOK 4096

typedef float        f32x16 __attribute__((ext_vector_type(16)));
typedef short        s16x8  __attribute__((ext_vector_type(8)));
typedef unsigned int u32x4  __attribute__((ext_vector_type(4)));

__device__ __forceinline__ unsigned short f2bf(float f) {
    __hip_bfloat16 h = __float2bfloat16(f);
    return *reinterpret_cast<unsigned short*>(&h);
}
__device__ __forceinline__ float bf2f(unsigned short u) {
    __hip_bfloat16 h = *reinterpret_cast<__hip_bfloat16*>(&u);
    return __bfloat162float(h);
}
__device__ __forceinline__ unsigned int pkbf(float a, float b) {
    return (unsigned int)f2bf(a) | ((unsigned int)f2bf(b) << 16);
}

// ---------------------------------------------------------------------------
// Kernel 1: QKV projection. One thread per voxel, weights in LDS.
// Outputs (all bf16):
//   qt2[b][i][16] = [q_hi(8) | q_lo(8)]   (32B rows)
//   kt2[b][i][16] = [k_hi(8) | k_lo(8)]
//   vt [b][c][i]  = V^T, bf16             (A-operand layout for PV MFMA)
// ---------------------------------------------------------------------------
__global__ __launch_bounds__(64)
void qkv_kernel(const float* __restrict__ x,
                const float* __restrict__ Wq, const float* __restrict__ bq,
                const float* __restrict__ Wk, const float* __restrict__ bk,
                const float* __restrict__ Wv, const float* __restrict__ bv,
                unsigned short* __restrict__ qt2, unsigned short* __restrict__ kt2,
                unsigned short* __restrict__ vt)
{
    __shared__ float wlds[80 * 64];   // rows 0-7: Wq, 8-15: Wk, 16-79: Wv
    __shared__ float blds[80];
    const int t = threadIdx.x;

    float4* w4 = (float4*)wlds;
    const float4* wq4 = (const float4*)Wq;
    const float4* wk4 = (const float4*)Wk;
    const float4* wv4 = (const float4*)Wv;
    #pragma unroll
    for (int r = 0; r < 2; r++)  w4[t + 64*r]        = wq4[t + 64*r];
    #pragma unroll
    for (int r = 0; r < 2; r++)  w4[128 + t + 64*r]  = wk4[t + 64*r];
    #pragma unroll
    for (int r = 0; r < 16; r++) w4[256 + t + 64*r]  = wv4[t + 64*r];
    if (t < 8)        blds[t] = bq[t];
    else if (t < 16)  blds[t] = bk[t - 8];
    blds[16 + t] = bv[t];
    __syncthreads();

    const int gid = blockIdx.x * 64 + t;
    const int b = gid >> 12;
    const int i = gid & (NTOK - 1);
    const float* xb = x + ((size_t)b * 64) * NTOK + i;
    float xv[64];
    #pragma unroll
    for (int c = 0; c < 64; c++) xv[c] = xb[(size_t)c * NTOK];

    const size_t row = (size_t)b * NTOK + i;
    for (int chunk = 0; chunk < 10; chunk++) {
        float a[8];
        #pragma unroll
        for (int o = 0; o < 8; o++) a[o] = blds[chunk*8 + o];
        #pragma unroll
        for (int c4 = 0; c4 < 16; c4++) {
            #pragma unroll
            for (int o = 0; o < 8; o++) {
                float4 w = ((const float4*)wlds)[(chunk*8 + o)*16 + c4];
                a[o] += w.x * xv[c4*4+0] + w.y * xv[c4*4+1]
                      + w.z * xv[c4*4+2] + w.w * xv[c4*4+3];
            }
        }
        if (chunk < 2) {
            unsigned short* dst = (chunk == 0 ? qt2 : kt2) + row * 16;
            #pragma unroll
            for (int o = 0; o < 8; o++) {
                unsigned short hu = f2bf(a[o]);
                dst[o]     = hu;
                dst[8 + o] = f2bf(a[o] - bf2f(hu));
            }
        } else {
            const int cbase = (chunk - 2) * 8;
            #pragma unroll
            for (int o = 0; o < 8; o++)
                vt[((size_t)b*64 + cbase + o) * NTOK + i] = f2bf(a[o]);
        }
    }
}

// ---------------------------------------------------------------------------
// Kernel 2: flash attention partial, full-MFMA. 1 wave per block, 32 queries.
// Swapped QK^T: S^T[j][q] = mfma(A=K_frag, B=Q_frag).  Lane l (q = l&31,
// h = l>>5) holds S^T rows j = (r&3)+8*(r>>2)+4h.  Hi/lo split: two MFMAs
// give s = k*q_hi + k_hi*q_lo (fp32-grade scores from bf16 hardware).
// P^T -> B-frag via pack + shfl_xor(32) + select.  PV: out^T[c][q] accumulated
// in two f32x16 D-frags (c 0..31 / 32..63).  j-split over grid (ji) for
// occupancy; partials (m, l, acc) written to workspace.
// ---------------------------------------------------------------------------
__global__ __launch_bounds__(64)
void attn_partial(const unsigned short* __restrict__ qt2,
                  const unsigned short* __restrict__ kt2,
                  const unsigned short* __restrict__ vt,
                  float* __restrict__ pacc, float* __restrict__ pm,
                  float* __restrict__ pl, int jlen)
{
    const int l     = threadIdx.x;
    const int lo31  = l & 31;
    const int h     = l >> 5;
    const int w     = blockIdx.x & 511;
    const int ji    = blockIdx.x >> 9;
    const int b     = w >> 7;
    const int qbase = (w & 127) << 5;
    const int j0    = ji * jlen;

    // Q B-frags (loaded once): B[k=8h+t][col=q]. B1 = [q_hi|q_hi], B2 = [q_lo|0]
    const unsigned short* qrow = qt2 + ((size_t)b * NTOK + qbase + lo31) * 16;
    s16x8 qB1 = *(const s16x8*)qrow;
    s16x8 qB2;
    if (h == 0) qB2 = *(const s16x8*)(qrow + 8);
    else        { u32x4 z = {0,0,0,0}; qB2 = __builtin_bit_cast(s16x8, z); }

    const unsigned short* kb = kt2 + (size_t)b * NTOK * 16 + (size_t)h * 8;
    const unsigned short* vb = vt  + (size_t)b * 64 * NTOK + (size_t)lo31 * NTOK + 8 * h;

    f32x16 accA, accB;
    #pragma unroll
    for (int r = 0; r < 16; r++) { accA[r] = 0.f; accB[r] = 0.f; }
    float m = -INFINITY, lsum = 0.f;

    for (int jt = j0; jt < j0 + jlen; jt += 32) {
        // K A-frag: A[row=j=jt+(l&31)][k=8h+t] -> row (jt+lo31), bytes h*16..
        s16x8 kf  = *(const s16x8*)(kb + (size_t)(jt + lo31) * 16);
        // V^T A-frags (issue early; L2-resident): lane reads 8 bf16 along j
        s16x8 v00 = *(const s16x8*)(vb + jt);
        s16x8 v01 = *(const s16x8*)(vb + jt + 16);
        s16x8 v10 = *(const s16x8*)(vb + (size_t)32 * NTOK + jt);
        s16x8 v11 = *(const s16x8*)(vb + (size_t)32 * NTOK + jt + 16);

        f32x16 s;
        #pragma unroll
        for (int r = 0; r < 16; r++) s[r] = 0.f;
        s = __builtin_amdgcn_mfma_f32_32x32x16_bf16(kf, qB1, s, 0, 0, 0);
        s = __builtin_amdgcn_mfma_f32_32x32x16_bf16(kf, qB2, s, 0, 0, 0);

        // ---- online softmax (per query q = l&31, values split across h) ----
        float smax = s[0];
        #pragma unroll
        for (int r = 1; r < 16; r++) smax = fmaxf(smax, s[r]);
        smax = fmaxf(smax, __shfl_xor(smax, 32));

        if (__any(smax > m + 8.f)) {          // defer-max (T13), THR=8
            const float mnew = fmaxf(m, smax);
            const float sc = __expf(m - mnew);
            #pragma unroll
            for (int r = 0; r < 16; r++) { accA[r] *= sc; accB[r] *= sc; }
            lsum *= sc;
            m = mnew;
        }

        float p[16]; float ps = 0.f;
        #pragma unroll
        for (int r = 0; r < 16; r++) { p[r] = __expf(s[r] - m); ps += p[r]; }
        ps += __shfl_xor(ps, 32);
        lsum += ps;

        // ---- P^T -> B-frags (j 0..15 and 16..31 of this chunk) ----
        u32x4 wa, wc;
        {
            unsigned X0 = pkbf(p[0], p[1]), X1 = pkbf(p[2], p[3]);
            unsigned Y0 = pkbf(p[4], p[5]), Y1 = pkbf(p[6], p[7]);
            unsigned X0s = __shfl_xor(X0, 32), X1s = __shfl_xor(X1, 32);
            unsigned Y0s = __shfl_xor(Y0, 32), Y1s = __shfl_xor(Y1, 32);
            wa.x = h ? Y0s : X0;   wa.y = h ? Y1s : X1;
            wa.z = h ? Y0  : X0s;  wa.w = h ? Y1  : X1s;
        }
        {
            unsigned X0 = pkbf(p[8], p[9]),  X1 = pkbf(p[10], p[11]);
            unsigned Y0 = pkbf(p[12], p[13]), Y1 = pkbf(p[14], p[15]);
            unsigned X0s = __shfl_xor(X0, 32), X1s = __shfl_xor(X1, 32);
            unsigned Y0s = __shfl_xor(Y0, 32), Y1s = __shfl_xor(Y1, 32);
            wc.x = h ? Y0s : X0;   wc.y = h ? Y1s : X1;
            wc.z = h ? Y0  : X0s;  wc.w = h ? Y1  : X1s;
        }
        s16x8 pf0 = __builtin_bit_cast(s16x8, wa);
        s16x8 pf1 = __builtin_bit_cast(s16x8, wc);

        accA = __builtin_amdgcn_mfma_f32_32x32x16_bf16(v00, pf0, accA, 0, 0, 0);
        accA = __builtin_amdgcn_mfma_f32_32x32x16_bf16(v01, pf1, accA, 0, 0, 0);
        accB = __builtin_amdgcn_mfma_f32_32x32x16_bf16(v10, pf0, accB, 0, 0, 0);
        accB = __builtin_amdgcn_mfma_f32_32x32x16_bf16(v11, pf1, accB, 0, 0, 0);
    }

    // ---- write partials: acc[c][q], m[q], l[q] ----
    float* accout = pacc + (size_t)(ji * 512 + w) * 64 * 32;
    #pragma unroll
    for (int r = 0; r < 16; r++) {
        const int c = (r & 3) + 8 * (r >> 2) + 4 * h;
        accout[c * 32 + lo31]        = accA[r];
        accout[(c + 32) * 32 + lo31] = accB[r];
    }
    if (h == 0) {
        pm[(size_t)(ji * 512 + w) * 32 + lo31] = m;
        pl[(size_t)(ji * 512 + w) * 32 + lo31] = lsum;
    }
}

// ---------------------------------------------------------------------------
// Kernel 3: merge j-split partials + epilogue (gamma*out/L + x).
// ---------------------------------------------------------------------------
template<int JS>
__global__ __launch_bounds__(256)
void merge_kernel(const float* __restrict__ pacc, const float* __restrict__ pm,
                  const float* __restrict__ pl, const float* __restrict__ x,
                  const float* __restrict__ gamma, float* __restrict__ out)
{
    const int w  = blockIdx.x;           // 0..511 (b*128 + qtile)
    const int t  = threadIdx.x;
    const int q  = t & 31;
    const int c0 = (t >> 5) << 3;
    const int b  = w >> 7;
    const int qbase = (w & 127) << 5;

    float mi[JS], li[JS];
    #pragma unroll
    for (int i = 0; i < JS; i++) {
        mi[i] = pm[((size_t)i * 512 + w) * 32 + q];
        li[i] = pl[((size_t)i * 512 + w) * 32 + q];
    }
    float M = mi[0];
    #pragma unroll
    for (int i = 1; i < JS; i++) M = fmaxf(M, mi[i]);
    float e[JS]; float L = 0.f;
    #pragma unroll
    for (int i = 0; i < JS; i++) { e[i] = __expf(mi[i] - M); L += li[i] * e[i]; }
    const float g = gamma[0] / L;

    #pragma unroll
    for (int cc = 0; cc < 8; cc++) {
        const int c = c0 + cc;
        float O = 0.f;
        #pragma unroll
        for (int i = 0; i < JS; i++)
            O += pacc[(((size_t)i * 512 + w) * 64 + c) * 32 + q] * e[i];
        const size_t off = ((size_t)b * 64 + c) * NTOK + qbase + q;
        out[off] = g * O + x[off];
    }
}

// ---------------------------------------------------------------------------
extern "C" void kernel_launch(void* const* d_in, const int* in_sizes, int n_in,
                              void* d_out, int out_size, void* d_ws, size_t ws_size,
                              hipStream_t stream) {
    const float* x     = (const float*)d_in[0];
    const float* Wq    = (const float*)d_in[1];
    const float* bq    = (const float*)d_in[2];
    const float* Wk    = (const float*)d_in[3];
    const float* bk    = (const float*)d_in[4];
    const float* Wv    = (const float*)d_in[5];
    const float* bv    = (const float*)d_in[6];
    const float* gamma = (const float*)d_in[7];
    float* out = (float*)d_out;

    unsigned short* qt2 = (unsigned short*)d_ws;            // 4*4096*16 bf16
    unsigned short* kt2 = qt2 + (size_t)4 * NTOK * 16;      // 4*4096*16 bf16
    unsigned short* vt  = kt2 + (size_t)4 * NTOK * 16;      // 4*64*4096 bf16
    float* pacc = (float*)(vt + (size_t)4 * 64 * NTOK);

    const size_t head = (size_t)4*NTOK*16*2*2 + (size_t)4*64*NTOK*2;         // 3 MB
    const size_t per  = (size_t)512*64*32*4 + (size_t)512*32*4*2;            // 4.125 MB
    const int js = (head + 4*per <= ws_size) ? 4
                 : (head + 2*per <= ws_size) ? 2 : 1;

    float* pm = pacc + (size_t)js * 512 * 64 * 32;
    float* pl = pm  + (size_t)js * 512 * 32;

    qkv_kernel<<<256, 64, 0, stream>>>(x, Wq, bq, Wk, bk, Wv, bv, qt2, kt2, vt);
    attn_partial<<<512 * js, 64, 0, stream>>>(qt2, kt2, vt, pacc, pm, pl, NTOK / js);
    if (js == 4)      merge_kernel<4><<<512, 256, 0, stream>>>(pacc, pm, pl, x, gamma, out);
    else if (js == 2) merge_kernel<2><<<512, 256, 0, stream>>>(pacc, pm, pl, x, gamma, out);
    else              merge_kernel<1><<<512, 256, 0, stream>>>(pacc, pm, pl, x, gamma, out);
}

// Round 3
// 54.161 us; speedup vs baseline: 5.7574x; 1.6896x over previous
//
#include <hip/hip_runtime.h>
#include <hip/hip_bf16.h>
#include <cmath>

#define NTOK 4096

typedef float        f32x16 __attribute__((ext_vector_type(16)));
typedef short        s16x8  __attribute__((ext_vector_type(8)));
typedef unsigned int u32x4  __attribute__((ext_vector_type(4)));

__device__ __forceinline__ unsigned short f2bf(float f) {
    __hip_bfloat16 h = __float2bfloat16(f);
    return *reinterpret_cast<unsigned short*>(&h);
}
__device__ __forceinline__ float bf2f(unsigned short u) {
    __hip_bfloat16 h = *reinterpret_cast<__hip_bfloat16*>(&u);
    return __bfloat162float(h);
}
__device__ __forceinline__ unsigned int pkbf(float a, float b) {
    return (unsigned int)f2bf(a) | ((unsigned int)f2bf(b) << 16);
}

// ---------------------------------------------------------------------------
// Kernel 1: QKV projection, chunk-split for occupancy.
// Grid 1280 = 256 voxel-groups x 5 parts; part p computes concat-rows
// [16p, 16p+16) of the 80-row stacked weight [Wq;Wk;Wv]. Each block stages
// only its 16 weight rows (4 KB LDS). 5 waves/CU instead of 1.
// Outputs (bf16): qt2[b][i][16]=[q_hi|q_lo], kt2 same, vt[b][c][i]=V^T.
// ---------------------------------------------------------------------------
__global__ __launch_bounds__(64)
void qkv_kernel(const float* __restrict__ x,
                const float* __restrict__ Wq, const float* __restrict__ bq,
                const float* __restrict__ Wk, const float* __restrict__ bk,
                const float* __restrict__ Wv, const float* __restrict__ bv,
                unsigned short* __restrict__ qt2, unsigned short* __restrict__ kt2,
                unsigned short* __restrict__ vt)
{
    __shared__ float wlds[16 * 64];
    __shared__ float blds[16];
    const int t    = threadIdx.x;
    const int part = blockIdx.x >> 8;    // 0..4
    const int vg   = blockIdx.x & 255;

    float4* w4 = (float4*)wlds;
    #pragma unroll
    for (int rr = 0; rr < 4; rr++) {
        const int idx  = rr * 64 + t;          // 0..255 float4 slots
        const int row  = part * 16 + (idx >> 4);
        const int col4 = idx & 15;
        const float* src = (row < 8)  ? (Wq + row * 64)
                         : (row < 16) ? (Wk + (row - 8) * 64)
                                      : (Wv + (row - 16) * 64);
        w4[idx] = ((const float4*)src)[col4];
    }
    if (t < 16) {
        const int row = part * 16 + t;
        blds[t] = (row < 8) ? bq[row] : (row < 16) ? bk[row - 8] : bv[row - 16];
    }
    __syncthreads();

    const int gid = vg * 64 + t;
    const int b = gid >> 12;
    const int i = gid & (NTOK - 1);
    const float* xb = x + ((size_t)b * 64) * NTOK + i;
    float xv[64];
    #pragma unroll
    for (int c = 0; c < 64; c++) xv[c] = xb[(size_t)c * NTOK];

    const size_t row = (size_t)b * NTOK + i;
    #pragma unroll
    for (int ch = 0; ch < 2; ch++) {
        const int chunk = part * 2 + ch;
        float a[8];
        #pragma unroll
        for (int o = 0; o < 8; o++) a[o] = blds[ch * 8 + o];
        #pragma unroll
        for (int c4 = 0; c4 < 16; c4++) {
            #pragma unroll
            for (int o = 0; o < 8; o++) {
                float4 wv4 = ((const float4*)wlds)[(ch * 8 + o) * 16 + c4];
                a[o] += wv4.x * xv[c4*4+0] + wv4.y * xv[c4*4+1]
                      + wv4.z * xv[c4*4+2] + wv4.w * xv[c4*4+3];
            }
        }
        if (chunk < 2) {
            unsigned short* dst = (chunk == 0 ? qt2 : kt2) + row * 16;
            #pragma unroll
            for (int o = 0; o < 8; o++) {
                unsigned short hu = f2bf(a[o]);
                dst[o]     = hu;
                dst[8 + o] = f2bf(a[o] - bf2f(hu));
            }
        } else {
            const int cbase = (chunk - 2) * 8;
            #pragma unroll
            for (int o = 0; o < 8; o++)
                vt[((size_t)b*64 + cbase + o) * NTOK + i] = f2bf(a[o]);
        }
    }
}

// ---------------------------------------------------------------------------
// Kernel 2: fused flash attention, full-MFMA, in-block j-split + LDS merge.
// Block = 8 waves on one 32-query tile; wave wv owns j in [wv*512, wv*512+512).
// Swapped QK^T (S^T = mfma(K, Q)) with hi/lo bf16 split for fp32-grade scores.
// P^T -> B-frag via pack + shfl_xor(32) + select. Register double-buffered
// K/V prefetch. 3-round LDS tree merge of (m, l, acc), fused epilogue
// gamma*acc/L + x. No global partials, no merge kernel.
// ---------------------------------------------------------------------------
__global__ __launch_bounds__(512, 4)
void attn_kernel(const unsigned short* __restrict__ qt2,
                 const unsigned short* __restrict__ kt2,
                 const unsigned short* __restrict__ vt,
                 const float* __restrict__ x,
                 const float* __restrict__ gamma,
                 float* __restrict__ out)
{
    __shared__ float slds[4][64][32];   // merge slots [c][q], 32 KB
    __shared__ float mlds[4][2][32];    // m, l per slot

    const int t    = threadIdx.x;
    const int l    = t & 63;
    const int wv   = t >> 6;
    const int lo31 = l & 31;
    const int h    = l >> 5;
    const int w     = blockIdx.x;
    const int b     = w >> 7;
    const int qbase = (w & 127) << 5;
    const int j0    = wv << 9;          // 512 j per wave

    // Q B-frags: B1 = [q_hi|q_hi], B2 = [q_lo|0]
    const unsigned short* qrow = qt2 + ((size_t)b * NTOK + qbase + lo31) * 16;
    s16x8 qB1 = *(const s16x8*)qrow;
    s16x8 qB2;
    if (h == 0) qB2 = *(const s16x8*)(qrow + 8);
    else        { u32x4 z = {0,0,0,0}; qB2 = __builtin_bit_cast(s16x8, z); }

    const unsigned short* kb = kt2 + (size_t)b * NTOK * 16 + (size_t)h * 8;
    const unsigned short* vb = vt  + (size_t)b * 64 * NTOK + (size_t)lo31 * NTOK + 8 * h;

    f32x16 accA, accB;
    #pragma unroll
    for (int r = 0; r < 16; r++) { accA[r] = 0.f; accB[r] = 0.f; }
    float m = -INFINITY, lsum = 0.f;

    // prefetch chunk 0
    s16x8 kf  = *(const s16x8*)(kb + (size_t)(j0 + lo31) * 16);
    s16x8 v00 = *(const s16x8*)(vb + j0);
    s16x8 v01 = *(const s16x8*)(vb + j0 + 16);
    s16x8 v10 = *(const s16x8*)(vb + (size_t)32 * NTOK + j0);
    s16x8 v11 = *(const s16x8*)(vb + (size_t)32 * NTOK + j0 + 16);

    for (int it = 0; it < 16; ++it) {
        const int jn = (it == 15) ? j0 : j0 + ((it + 1) << 5);
        s16x8 kfn  = *(const s16x8*)(kb + (size_t)(jn + lo31) * 16);
        s16x8 v00n = *(const s16x8*)(vb + jn);
        s16x8 v01n = *(const s16x8*)(vb + jn + 16);
        s16x8 v10n = *(const s16x8*)(vb + (size_t)32 * NTOK + jn);
        s16x8 v11n = *(const s16x8*)(vb + (size_t)32 * NTOK + jn + 16);

        f32x16 s;
        #pragma unroll
        for (int r = 0; r < 16; r++) s[r] = 0.f;
        s = __builtin_amdgcn_mfma_f32_32x32x16_bf16(kf, qB1, s, 0, 0, 0);
        s = __builtin_amdgcn_mfma_f32_32x32x16_bf16(kf, qB2, s, 0, 0, 0);

        float smax = s[0];
        #pragma unroll
        for (int r = 1; r < 16; r++) smax = fmaxf(smax, s[r]);
        smax = fmaxf(smax, __shfl_xor(smax, 32));

        if (__any(smax > m + 8.f)) {          // defer-max (T13)
            const float mnew = fmaxf(m, smax);
            const float sc = __expf(m - mnew);
            #pragma unroll
            for (int r = 0; r < 16; r++) { accA[r] *= sc; accB[r] *= sc; }
            lsum *= sc;
            m = mnew;
        }

        float ps = 0.f;
        #pragma unroll
        for (int r = 0; r < 16; r++) { const float p = __expf(s[r] - m); ps += p; s[r] = p; }
        ps += __shfl_xor(ps, 32);
        lsum += ps;

        // P^T -> B-frags
        u32x4 wa, wc;
        {
            unsigned X0 = pkbf(s[0], s[1]), X1 = pkbf(s[2], s[3]);
            unsigned Y0 = pkbf(s[4], s[5]), Y1 = pkbf(s[6], s[7]);
            unsigned X0s = __shfl_xor(X0, 32), X1s = __shfl_xor(X1, 32);
            unsigned Y0s = __shfl_xor(Y0, 32), Y1s = __shfl_xor(Y1, 32);
            wa.x = h ? Y0s : X0;   wa.y = h ? Y1s : X1;
            wa.z = h ? Y0  : X0s;  wa.w = h ? Y1  : X1s;
        }
        {
            unsigned X0 = pkbf(s[8], s[9]),   X1 = pkbf(s[10], s[11]);
            unsigned Y0 = pkbf(s[12], s[13]), Y1 = pkbf(s[14], s[15]);
            unsigned X0s = __shfl_xor(X0, 32), X1s = __shfl_xor(X1, 32);
            unsigned Y0s = __shfl_xor(Y0, 32), Y1s = __shfl_xor(Y1, 32);
            wc.x = h ? Y0s : X0;   wc.y = h ? Y1s : X1;
            wc.z = h ? Y0  : X0s;  wc.w = h ? Y1  : X1s;
        }
        s16x8 pf0 = __builtin_bit_cast(s16x8, wa);
        s16x8 pf1 = __builtin_bit_cast(s16x8, wc);

        accA = __builtin_amdgcn_mfma_f32_32x32x16_bf16(v00, pf0, accA, 0, 0, 0);
        accA = __builtin_amdgcn_mfma_f32_32x32x16_bf16(v01, pf1, accA, 0, 0, 0);
        accB = __builtin_amdgcn_mfma_f32_32x32x16_bf16(v10, pf0, accB, 0, 0, 0);
        accB = __builtin_amdgcn_mfma_f32_32x32x16_bf16(v11, pf1, accB, 0, 0, 0);

        kf = kfn; v00 = v00n; v01 = v01n; v10 = v10n; v11 = v11n;
    }

    // ---- 3-round LDS tree merge of 8 wave-partials ----
    #define WR_SLOT(sidx) do {                                                \
        const int s_ = (sidx);                                                \
        _Pragma("unroll")                                                     \
        for (int r = 0; r < 16; r++) {                                        \
            const int c_ = (r & 3) + 8 * (r >> 2) + 4 * h;                    \
            slds[s_][c_][lo31]      = accA[r];                                \
            slds[s_][c_ + 32][lo31] = accB[r];                                \
        }                                                                     \
        if (h == 0) { mlds[s_][0][lo31] = m; mlds[s_][1][lo31] = lsum; }      \
    } while (0)

    #define MRG_SLOT(sidx) do {                                               \
        const int s_ = (sidx);                                                \
        const float mo_ = mlds[s_][0][lo31];                                  \
        const float lo_ = mlds[s_][1][lo31];                                  \
        const float M_  = fmaxf(m, mo_);                                      \
        const float eS_ = __expf(m - M_), eO_ = __expf(mo_ - M_);             \
        _Pragma("unroll")                                                     \
        for (int r = 0; r < 16; r++) {                                        \
            const int c_ = (r & 3) + 8 * (r >> 2) + 4 * h;                    \
            accA[r] = accA[r] * eS_ + slds[s_][c_][lo31] * eO_;               \
            accB[r] = accB[r] * eS_ + slds[s_][c_ + 32][lo31] * eO_;          \
        }                                                                     \
        lsum = lsum * eS_ + lo_ * eO_;                                        \
        m = M_;                                                               \
    } while (0)

    if (wv >= 4) WR_SLOT(wv - 4);
    __syncthreads();
    if (wv < 4) MRG_SLOT(wv);
    __syncthreads();
    if (wv == 2 || wv == 3) WR_SLOT(wv - 2);
    __syncthreads();
    if (wv < 2) MRG_SLOT(wv);
    __syncthreads();
    if (wv == 1) WR_SLOT(0);
    __syncthreads();
    if (wv == 0) { MRG_SLOT(0); WR_SLOT(0); }
    __syncthreads();

    // ---- fused epilogue: out = gamma*acc/L + x, all 512 threads ----
    const int c  = t >> 3;
    const int q4 = (t & 7) << 2;
    const float g = gamma[0];
    const float4 a4 = *(const float4*)&slds[0][c][q4];
    const float g0 = g / mlds[0][1][q4 + 0];
    const float g1 = g / mlds[0][1][q4 + 1];
    const float g2 = g / mlds[0][1][q4 + 2];
    const float g3 = g / mlds[0][1][q4 + 3];
    const size_t off = (((size_t)b * 64 + c) << 12) + qbase + q4;
    const float4 xv4 = *(const float4*)(x + off);
    float4 o;
    o.x = a4.x * g0 + xv4.x;
    o.y = a4.y * g1 + xv4.y;
    o.z = a4.z * g2 + xv4.z;
    o.w = a4.w * g3 + xv4.w;
    *(float4*)(out + off) = o;
}

// ---------------------------------------------------------------------------
extern "C" void kernel_launch(void* const* d_in, const int* in_sizes, int n_in,
                              void* d_out, int out_size, void* d_ws, size_t ws_size,
                              hipStream_t stream) {
    const float* x     = (const float*)d_in[0];
    const float* Wq    = (const float*)d_in[1];
    const float* bq    = (const float*)d_in[2];
    const float* Wk    = (const float*)d_in[3];
    const float* bk    = (const float*)d_in[4];
    const float* Wv    = (const float*)d_in[5];
    const float* bv    = (const float*)d_in[6];
    const float* gamma = (const float*)d_in[7];
    float* out = (float*)d_out;

    unsigned short* qt2 = (unsigned short*)d_ws;            // 4*4096*16 bf16
    unsigned short* kt2 = qt2 + (size_t)4 * NTOK * 16;      // 4*4096*16 bf16
    unsigned short* vt  = kt2 + (size_t)4 * NTOK * 16;      // 4*64*4096 bf16

    qkv_kernel<<<1280, 64, 0, stream>>>(x, Wq, bq, Wk, bk, Wv, bv, qt2, kt2, vt);
    attn_kernel<<<512, 512, 0, stream>>>(qt2, kt2, vt, x, gamma, out);
}

// Round 4
// 51.442 us; speedup vs baseline: 6.0617x; 1.0529x over previous
//
#include <hip/hip_runtime.h>
#include <hip/hip_bf16.h>
#include <cmath>

#define NTOK 4096

typedef float        f32x16 __attribute__((ext_vector_type(16)));
typedef short        s16x8  __attribute__((ext_vector_type(8)));
typedef unsigned int u32x4  __attribute__((ext_vector_type(4)));

__device__ __forceinline__ unsigned short f2bf(float f) {
    __hip_bfloat16 h = __float2bfloat16(f);
    return *reinterpret_cast<unsigned short*>(&h);
}
__device__ __forceinline__ float bf2f(unsigned short u) {
    __hip_bfloat16 h = *reinterpret_cast<__hip_bfloat16*>(&u);
    return __bfloat162float(h);
}
__device__ __forceinline__ unsigned int pkbf(float a, float b) {
    return (unsigned int)f2bf(a) | ((unsigned int)f2bf(b) << 16);
}

// ---------------------------------------------------------------------------
// Kernel 1: QKV projection, chunk-split for occupancy (grid 1280 = 256 x 5).
// Outputs (bf16):
//   qt2[b][i][16] = [q_hi(8) | q_lo(8)]  -- packed 32B/lane contiguous stores
//   kt2 same
//   vt  [b][i/16][c][i%16]               -- 16-j tiled V^T so the attention
//       PV A-frag load (c = lane&31, k = 8h..8h+8) is a contiguous 1KB/instr.
// ---------------------------------------------------------------------------
__global__ __launch_bounds__(64)
void qkv_kernel(const float* __restrict__ x,
                const float* __restrict__ Wq, const float* __restrict__ bq,
                const float* __restrict__ Wk, const float* __restrict__ bk,
                const float* __restrict__ Wv, const float* __restrict__ bv,
                unsigned short* __restrict__ qt2, unsigned short* __restrict__ kt2,
                unsigned short* __restrict__ vt)
{
    __shared__ float wlds[16 * 64];
    __shared__ float blds[16];
    const int t    = threadIdx.x;
    const int part = blockIdx.x >> 8;    // 0..4
    const int vg   = blockIdx.x & 255;

    float4* w4 = (float4*)wlds;
    #pragma unroll
    for (int rr = 0; rr < 4; rr++) {
        const int idx  = rr * 64 + t;          // 0..255 float4 slots
        const int row  = part * 16 + (idx >> 4);
        const int col4 = idx & 15;
        const float* src = (row < 8)  ? (Wq + row * 64)
                         : (row < 16) ? (Wk + (row - 8) * 64)
                                      : (Wv + (row - 16) * 64);
        w4[idx] = ((const float4*)src)[col4];
    }
    if (t < 16) {
        const int row = part * 16 + t;
        blds[t] = (row < 8) ? bq[row] : (row < 16) ? bk[row - 8] : bv[row - 16];
    }
    __syncthreads();

    const int gid = vg * 64 + t;
    const int b = gid >> 12;
    const int i = gid & (NTOK - 1);
    const float* xb = x + ((size_t)b * 64) * NTOK + i;
    float xv[64];
    #pragma unroll
    for (int c = 0; c < 64; c++) xv[c] = xb[(size_t)c * NTOK];

    const size_t row = (size_t)b * NTOK + i;
    #pragma unroll
    for (int ch = 0; ch < 2; ch++) {
        const int chunk = part * 2 + ch;
        float a[8];
        #pragma unroll
        for (int o = 0; o < 8; o++) a[o] = blds[ch * 8 + o];
        #pragma unroll
        for (int c4 = 0; c4 < 16; c4++) {
            #pragma unroll
            for (int o = 0; o < 8; o++) {
                float4 wv4 = ((const float4*)wlds)[(ch * 8 + o) * 16 + c4];
                a[o] += wv4.x * xv[c4*4+0] + wv4.y * xv[c4*4+1]
                      + wv4.z * xv[c4*4+2] + wv4.w * xv[c4*4+3];
            }
        }
        if (chunk < 2) {
            unsigned short hu[8], lu[8];
            #pragma unroll
            for (int o = 0; o < 8; o++) {
                hu[o] = f2bf(a[o]);
                lu[o] = f2bf(a[o] - bf2f(hu[o]));
            }
            unsigned short* dst = (chunk == 0 ? qt2 : kt2) + row * 16;
            ((u32x4*)dst)[0] = *(const u32x4*)hu;
            ((u32x4*)dst)[1] = *(const u32x4*)lu;
        } else {
            const int cbase = (chunk - 2) * 8;
            unsigned short* vdst =
                vt + ((size_t)b * 256 + (i >> 4)) * 1024 + (size_t)cbase * 16 + (i & 15);
            #pragma unroll
            for (int o = 0; o < 8; o++)
                vdst[o * 16] = f2bf(a[o]);
        }
    }
}

// ---------------------------------------------------------------------------
// Kernel 2: fused flash attention, full-MFMA, in-block j-split + LDS merge.
// Block = 8 waves on one 32-query tile; wave wv owns j in [wv*512, wv*512+512).
// Swapped QK^T (S^T = mfma(K, Q)) with hi/lo bf16 split for fp32-grade scores.
// All K and V global loads are contiguous 1KB-per-instruction (V via the
// 16-j-tiled layout). Register double-buffered prefetch; 3-round LDS tree
// merge; fused epilogue gamma*acc/L + x.
// ---------------------------------------------------------------------------
__global__ __launch_bounds__(512, 4)
void attn_kernel(const unsigned short* __restrict__ qt2,
                 const unsigned short* __restrict__ kt2,
                 const unsigned short* __restrict__ vt,
                 const float* __restrict__ x,
                 const float* __restrict__ gamma,
                 float* __restrict__ out)
{
    __shared__ float slds[4][64][32];   // merge slots [c][q], 32 KB
    __shared__ float mlds[4][2][32];    // m, l per slot

    const int t    = threadIdx.x;
    const int l    = t & 63;
    const int wv   = t >> 6;
    const int lo31 = l & 31;
    const int h    = l >> 5;
    const int w     = blockIdx.x;
    const int b     = w >> 7;
    const int qbase = (w & 127) << 5;
    const int j0    = wv << 9;          // 512 j per wave

    // Q B-frags: B1 = [q_hi|q_hi], B2 = [q_lo|0]
    const unsigned short* qrow = qt2 + ((size_t)b * NTOK + qbase + lo31) * 16;
    s16x8 qB1 = *(const s16x8*)qrow;
    s16x8 qB2;
    if (h == 0) qB2 = *(const s16x8*)(qrow + 8);
    else        { u32x4 z = {0,0,0,0}; qB2 = __builtin_bit_cast(s16x8, z); }

    const unsigned short* kb  = kt2 + (size_t)b * NTOK * 16 + (size_t)h * 8;
    // V^T tiled: vt[b][t16][c][jj]; lane base for accA (c=lo31) / accB (+32)
    const unsigned short* vbA = vt + (size_t)b * NTOK * 64 + (size_t)lo31 * 16 + 8 * h;
    const unsigned short* vbB = vbA + 512;

    f32x16 accA, accB;
    #pragma unroll
    for (int r = 0; r < 16; r++) { accA[r] = 0.f; accB[r] = 0.f; }
    float m = -INFINITY, lsum = 0.f;

    // prefetch chunk 0  (tile index = j>>4, stride 1024 shorts per tile)
    s16x8 kf  = *(const s16x8*)(kb + (size_t)(j0 + lo31) * 16);
    s16x8 v00 = *(const s16x8*)(vbA + (size_t)(j0 >> 4) * 1024);
    s16x8 v01 = *(const s16x8*)(vbA + (size_t)((j0 >> 4) + 1) * 1024);
    s16x8 v10 = *(const s16x8*)(vbB + (size_t)(j0 >> 4) * 1024);
    s16x8 v11 = *(const s16x8*)(vbB + (size_t)((j0 >> 4) + 1) * 1024);

    for (int it = 0; it < 16; ++it) {
        const int jn = (it == 15) ? j0 : j0 + ((it + 1) << 5);
        s16x8 kfn  = *(const s16x8*)(kb + (size_t)(jn + lo31) * 16);
        s16x8 v00n = *(const s16x8*)(vbA + (size_t)(jn >> 4) * 1024);
        s16x8 v01n = *(const s16x8*)(vbA + (size_t)((jn >> 4) + 1) * 1024);
        s16x8 v10n = *(const s16x8*)(vbB + (size_t)(jn >> 4) * 1024);
        s16x8 v11n = *(const s16x8*)(vbB + (size_t)((jn >> 4) + 1) * 1024);

        f32x16 s;
        #pragma unroll
        for (int r = 0; r < 16; r++) s[r] = 0.f;
        s = __builtin_amdgcn_mfma_f32_32x32x16_bf16(kf, qB1, s, 0, 0, 0);
        s = __builtin_amdgcn_mfma_f32_32x32x16_bf16(kf, qB2, s, 0, 0, 0);

        float smax = s[0];
        #pragma unroll
        for (int r = 1; r < 16; r++) smax = fmaxf(smax, s[r]);
        smax = fmaxf(smax, __shfl_xor(smax, 32));

        if (__any(smax > m + 8.f)) {          // defer-max (T13)
            const float mnew = fmaxf(m, smax);
            const float sc = __expf(m - mnew);
            #pragma unroll
            for (int r = 0; r < 16; r++) { accA[r] *= sc; accB[r] *= sc; }
            lsum *= sc;
            m = mnew;
        }

        float ps = 0.f;
        #pragma unroll
        for (int r = 0; r < 16; r++) { const float p = __expf(s[r] - m); ps += p; s[r] = p; }
        ps += __shfl_xor(ps, 32);
        lsum += ps;

        // P^T -> B-frags
        u32x4 wa, wc;
        {
            unsigned X0 = pkbf(s[0], s[1]), X1 = pkbf(s[2], s[3]);
            unsigned Y0 = pkbf(s[4], s[5]), Y1 = pkbf(s[6], s[7]);
            unsigned X0s = __shfl_xor(X0, 32), X1s = __shfl_xor(X1, 32);
            unsigned Y0s = __shfl_xor(Y0, 32), Y1s = __shfl_xor(Y1, 32);
            wa.x = h ? Y0s : X0;   wa.y = h ? Y1s : X1;
            wa.z = h ? Y0  : X0s;  wa.w = h ? Y1  : X1s;
        }
        {
            unsigned X0 = pkbf(s[8], s[9]),   X1 = pkbf(s[10], s[11]);
            unsigned Y0 = pkbf(s[12], s[13]), Y1 = pkbf(s[14], s[15]);
            unsigned X0s = __shfl_xor(X0, 32), X1s = __shfl_xor(X1, 32);
            unsigned Y0s = __shfl_xor(Y0, 32), Y1s = __shfl_xor(Y1, 32);
            wc.x = h ? Y0s : X0;   wc.y = h ? Y1s : X1;
            wc.z = h ? Y0  : X0s;  wc.w = h ? Y1  : X1s;
        }
        s16x8 pf0 = __builtin_bit_cast(s16x8, wa);
        s16x8 pf1 = __builtin_bit_cast(s16x8, wc);

        accA = __builtin_amdgcn_mfma_f32_32x32x16_bf16(v00, pf0, accA, 0, 0, 0);
        accA = __builtin_amdgcn_mfma_f32_32x32x16_bf16(v01, pf1, accA, 0, 0, 0);
        accB = __builtin_amdgcn_mfma_f32_32x32x16_bf16(v10, pf0, accB, 0, 0, 0);
        accB = __builtin_amdgcn_mfma_f32_32x32x16_bf16(v11, pf1, accB, 0, 0, 0);

        kf = kfn; v00 = v00n; v01 = v01n; v10 = v10n; v11 = v11n;
    }

    // ---- 3-round LDS tree merge of 8 wave-partials ----
    #define WR_SLOT(sidx) do {                                                \
        const int s_ = (sidx);                                                \
        _Pragma("unroll")                                                     \
        for (int r = 0; r < 16; r++) {                                        \
            const int c_ = (r & 3) + 8 * (r >> 2) + 4 * h;                    \
            slds[s_][c_][lo31]      = accA[r];                                \
            slds[s_][c_ + 32][lo31] = accB[r];                                \
        }                                                                     \
        if (h == 0) { mlds[s_][0][lo31] = m; mlds[s_][1][lo31] = lsum; }      \
    } while (0)

    #define MRG_SLOT(sidx) do {                                               \
        const int s_ = (sidx);                                                \
        const float mo_ = mlds[s_][0][lo31];                                  \
        const float lo_ = mlds[s_][1][lo31];                                  \
        const float M_  = fmaxf(m, mo_);                                      \
        const float eS_ = __expf(m - M_), eO_ = __expf(mo_ - M_);             \
        _Pragma("unroll")                                                     \
        for (int r = 0; r < 16; r++) {                                        \
            const int c_ = (r & 3) + 8 * (r >> 2) + 4 * h;                    \
            accA[r] = accA[r] * eS_ + slds[s_][c_][lo31] * eO_;               \
            accB[r] = accB[r] * eS_ + slds[s_][c_ + 32][lo31] * eO_;          \
        }                                                                     \
        lsum = lsum * eS_ + lo_ * eO_;                                        \
        m = M_;                                                               \
    } while (0)

    if (wv >= 4) WR_SLOT(wv - 4);
    __syncthreads();
    if (wv < 4) MRG_SLOT(wv);
    __syncthreads();
    if (wv == 2 || wv == 3) WR_SLOT(wv - 2);
    __syncthreads();
    if (wv < 2) MRG_SLOT(wv);
    __syncthreads();
    if (wv == 1) WR_SLOT(0);
    __syncthreads();
    if (wv == 0) { MRG_SLOT(0); WR_SLOT(0); }
    __syncthreads();

    // ---- fused epilogue: out = gamma*acc/L + x, all 512 threads ----
    const int c  = t >> 3;
    const int q4 = (t & 7) << 2;
    const float g = gamma[0];
    const float4 a4 = *(const float4*)&slds[0][c][q4];
    const float g0 = g / mlds[0][1][q4 + 0];
    const float g1 = g / mlds[0][1][q4 + 1];
    const float g2 = g / mlds[0][1][q4 + 2];
    const float g3 = g / mlds[0][1][q4 + 3];
    const size_t off = (((size_t)b * 64 + c) << 12) + qbase + q4;
    const float4 xv4 = *(const float4*)(x + off);
    float4 o;
    o.x = a4.x * g0 + xv4.x;
    o.y = a4.y * g1 + xv4.y;
    o.z = a4.z * g2 + xv4.z;
    o.w = a4.w * g3 + xv4.w;
    *(float4*)(out + off) = o;
}

// ---------------------------------------------------------------------------
extern "C" void kernel_launch(void* const* d_in, const int* in_sizes, int n_in,
                              void* d_out, int out_size, void* d_ws, size_t ws_size,
                              hipStream_t stream) {
    const float* x     = (const float*)d_in[0];
    const float* Wq    = (const float*)d_in[1];
    const float* bq    = (const float*)d_in[2];
    const float* Wk    = (const float*)d_in[3];
    const float* bk    = (const float*)d_in[4];
    const float* Wv    = (const float*)d_in[5];
    const float* bv    = (const float*)d_in[6];
    const float* gamma = (const float*)d_in[7];
    float* out = (float*)d_out;

    unsigned short* qt2 = (unsigned short*)d_ws;            // 4*4096*16 bf16
    unsigned short* kt2 = qt2 + (size_t)4 * NTOK * 16;      // 4*4096*16 bf16
    unsigned short* vt  = kt2 + (size_t)4 * NTOK * 16;      // 4*4096*64 bf16 (tiled)

    qkv_kernel<<<1280, 64, 0, stream>>>(x, Wq, bq, Wk, bk, Wv, bv, qt2, kt2, vt);
    attn_kernel<<<512, 512, 0, stream>>>(qt2, kt2, vt, x, gamma, out);
}